// Round 5
// baseline (364.162 us; speedup 1.0000x reference)
//
#include <hip/hip_runtime.h>

#define BINS 10
#define COPIES 64      // one histogram copy per lane id (waves share via LDS atomics)
#define HSTRIDE 11     // 10 bins + 1 pad (odd stride breaks power-of-2 bank aliasing)

// Algebra: q = t?p:(1-p) = 1-|p-t| = 1-g, so bce = -log(1-g) = -ln2*log2(1-g).
// Accumulate log2(1-g); fold -ln2 in finalize. Per elem: ~7 VALU + 2 DS ops.
__device__ __forceinline__ void elem(float p, float t,
                                     float* __restrict__ ssum,
                                     unsigned int* __restrict__ scnt,
                                     int lane_off)
{
    float g  = fabsf(p - t);          // same expr as reference
    float l2 = __log2f(1.0f - g);     // v_log_f32
    int   bi = (int)(g * 10.0f);      // g in (0.01,0.99): bi in [0,9], no clamp
    int idx = lane_off + bi;
    __hip_atomic_fetch_add(&ssum[idx], l2, __ATOMIC_RELAXED,
                           __HIP_MEMORY_SCOPE_WORKGROUP);
    __hip_atomic_fetch_add(&scnt[idx], 1u, __ATOMIC_RELAXED,
                           __HIP_MEMORY_SCOPE_WORKGROUP);
}

__device__ __forceinline__ void proc8(const float4 pa, const float4 pb,
                                      const float4 ta, const float4 tb,
                                      float* __restrict__ ssum,
                                      unsigned int* __restrict__ scnt,
                                      int lane_off)
{
    elem(pa.x, ta.x, ssum, scnt, lane_off); elem(pa.y, ta.y, ssum, scnt, lane_off);
    elem(pa.z, ta.z, ssum, scnt, lane_off); elem(pa.w, ta.w, ssum, scnt, lane_off);
    elem(pb.x, tb.x, ssum, scnt, lane_off); elem(pb.y, tb.y, ssum, scnt, lane_off);
    elem(pb.z, tb.z, ssum, scnt, lane_off); elem(pb.w, tb.w, ssum, scnt, lane_off);
}

__global__ __launch_bounds__(256, 4) void ghm_partial(
    const float4* __restrict__ p4,
    const float4* __restrict__ t4,
    float* __restrict__ gsum,          // [BINS] floats in d_ws
    unsigned int* __restrict__ gcnt,   // [BINS] uints in d_ws
    int n4)
{
    __shared__ float        s_sum[COPIES * HSTRIDE];
    __shared__ unsigned int s_cnt[COPIES * HSTRIDE];

    const int tid = threadIdx.x;
    for (int k = tid; k < COPIES * HSTRIDE; k += 256) {
        s_sum[k] = 0.0f;
        s_cnt[k] = 0u;
    }
    __syncthreads();

    const int lane_off = (tid & 63) * HSTRIDE;
    const int start    = blockIdx.x * blockDim.x + tid;
    const int stride   = gridDim.x * blockDim.x;
    const int stride2  = 2 * stride;
    const int nouter   = n4 / stride2;   // 8 at 2048x256, n4 = 2^23

    // depth-2 pipeline, 2 float4-pairs per stage: 8 loads (128 B) in flight
    if (nouter >= 2) {
        int i = start;
        float4 pa0 = p4[i], pb0 = p4[i + stride];
        float4 ta0 = t4[i], tb0 = t4[i + stride];
        i += stride2;
        float4 pa1 = p4[i], pb1 = p4[i + stride];
        float4 ta1 = t4[i], tb1 = t4[i + stride];
        i += stride2;
        for (int it = 0; it < nouter - 2; ++it, i += stride2) {
            float4 na = p4[i], nb = p4[i + stride];   // prefetch next stage
            float4 ma = t4[i], mb = t4[i + stride];
            proc8(pa0, pb0, ta0, tb0, s_sum, s_cnt, lane_off);
            pa0 = pa1; pb0 = pb1; ta0 = ta1; tb0 = tb1;
            pa1 = na;  pb1 = nb;  ta1 = ma;  tb1 = mb;
        }
        proc8(pa0, pb0, ta0, tb0, s_sum, s_cnt, lane_off);
        proc8(pa1, pb1, ta1, tb1, s_sum, s_cnt, lane_off);
    } else {
        for (int k = 0; k < 2 * nouter; ++k) {
            int i = start + k * stride;
            float4 p = p4[i], t = t4[i];
            elem(p.x, t.x, s_sum, s_cnt, lane_off);
            elem(p.y, t.y, s_sum, s_cnt, lane_off);
            elem(p.z, t.z, s_sum, s_cnt, lane_off);
            elem(p.w, t.w, s_sum, s_cnt, lane_off);
        }
    }
    // tail (n4 not divisible by 2*stride)
    for (int j = start + nouter * stride2; j < n4; j += stride) {
        float4 p = p4[j], t = t4[j];
        elem(p.x, t.x, s_sum, s_cnt, lane_off);
        elem(p.y, t.y, s_sum, s_cnt, lane_off);
        elem(p.z, t.z, s_sum, s_cnt, lane_off);
        elem(p.w, t.w, s_sum, s_cnt, lane_off);
    }

    __syncthreads();
    // reduce the 64 copies; lanes 0-9 sums, lanes 16-25 counts (parallel)
    if (tid < BINS) {
        float s = 0.0f;
#pragma unroll
        for (int l = 0; l < COPIES; ++l) s += s_sum[l * HSTRIDE + tid];
        atomicAdd(&gsum[tid], s);
    }
    if (tid >= 16 && tid < 16 + BINS) {
        const int b = tid - 16;
        unsigned int c = 0u;
#pragma unroll
        for (int l = 0; l < COPIES; ++l) c += s_cnt[l * HSTRIDE + b];
        atomicAdd(&gcnt[b], c);
    }
}

__global__ void ghm_finalize(const float* __restrict__ gsum,
                             const unsigned int* __restrict__ gcnt,
                             float* __restrict__ out)
{
    if (threadIdx.x == 0 && blockIdx.x == 0) {
        int n = 0;
#pragma unroll
        for (int b = 0; b < BINS; ++b) n += (gcnt[b] > 0u) ? 1 : 0;
        float nn = (float)(n > 0 ? n : 1);
        float acc = 0.0f;
#pragma unroll
        for (int b = 0; b < BINS; ++b) {
            if (gcnt[b] > 0u)
                acc += gsum[b] / ((float)gcnt[b] * nn);  // counts < 2^24: exact
        }
        out[0] = -0.6931471805599453f * acc;   // fold -ln(2) from log2 domain
    }
}

extern "C" void kernel_launch(void* const* d_in, const int* in_sizes, int n_in,
                              void* d_out, int out_size, void* d_ws, size_t ws_size,
                              hipStream_t stream)
{
    const float* p = (const float*)d_in[0];   // inputs (probabilities)
    const float* t = (const float*)d_in[1];   // targets (0/1 floats)
    const int n  = in_sizes[0];               // 262144*128
    const int n4 = n >> 2;                    // divisible by 4

    float*        gsum = (float*)d_ws;
    unsigned int* gcnt = (unsigned int*)((char*)d_ws + BINS * sizeof(float));

    // d_ws is re-poisoned to 0xAA before every timed launch — zero it (capturable)
    hipMemsetAsync(d_ws, 0, BINS * (sizeof(float) + sizeof(unsigned int)), stream);

    const int threads = 256;
    const int blocks  = 2048;   // nouter = 8 exactly at n4 = 2^23
    ghm_partial<<<blocks, threads, 0, stream>>>(
        (const float4*)p, (const float4*)t, gsum, gcnt, n4);

    ghm_finalize<<<1, 64, 0, stream>>>(gsum, gcnt, (float*)d_out);
}

// Round 6
// 292.867 us; speedup vs baseline: 1.2434x; 1.2434x over previous
//
#include <hip/hip_runtime.h>

#define BINS 10

// Per-element update (identical arithmetic to R3, absmax == 0).
// q = t?p:(1-p) = 1-|p-t| = 1-g, bce = -log(1-g) = -ln2*log2(1-g);
// accumulate log2(1-g), fold -ln2 in finalize.
// Counts via ballot -> s_bcnt1 on the scalar pipe (shares the v_cmp).
__device__ __forceinline__ void elem(float p, float t,
                                     float* __restrict__ sb,
                                     unsigned int* __restrict__ cw)
{
    float g  = fabsf(p - t);
    float l2 = __log2f(1.0f - g);
    int   bi = (int)(g * 10.0f);      // g in (0.01,0.99): bi in [0,9]
#pragma unroll
    for (int b = 0; b < BINS; ++b) {
        bool hit = (bi == b);                   // one v_cmp -> sgpr pair
        unsigned long long m = __ballot(hit);   // reuses the compare
        sb[b] += hit ? l2 : 0.0f;               // cndmask + add
        cw[b] += (unsigned int)__popcll(m);     // scalar pipe
    }
}

__device__ __forceinline__ void proc4v(const float4 p, const float4 t,
                                       float* __restrict__ sb,
                                       unsigned int* __restrict__ cw)
{
    elem(p.x, t.x, sb, cw); elem(p.y, t.y, sb, cw);
    elem(p.z, t.z, sb, cw); elem(p.w, t.w, sb, cw);
}

__global__ __launch_bounds__(256, 4) void ghm_partial(
    const float4* __restrict__ p4,
    const float4* __restrict__ t4,
    float* __restrict__ gsum,          // [BINS] floats in d_ws
    unsigned int* __restrict__ gcnt,   // [BINS] uints in d_ws
    int n4)
{
    float        sb[BINS];
    unsigned int cw[BINS];
#pragma unroll
    for (int b = 0; b < BINS; ++b) { sb[b] = 0.0f; cw[b] = 0u; }

    const int tid    = threadIdx.x;
    const int start  = blockIdx.x * blockDim.x + tid;
    const int stride = gridDim.x * blockDim.x;
    const int ngrp   = n4 / (4 * stride);   // 4 at 2048x256, n4 = 2^23

    // Bulk-load groups: 8 interleaved dwordx4 loads (128 B/thread in flight),
    // then a scheduling fence so the compiler cannot sink loads into compute.
    // First consumer waits at vmcnt(6); later pairs drain progressively.
    int i = start;
    for (int grp = 0; grp < ngrp; ++grp, i += 4 * stride) {
        float4 P0 = p4[i];
        float4 T0 = t4[i];
        float4 P1 = p4[i + stride];
        float4 T1 = t4[i + stride];
        float4 P2 = p4[i + 2 * stride];
        float4 T2 = t4[i + 2 * stride];
        float4 P3 = p4[i + 3 * stride];
        float4 T3 = t4[i + 3 * stride];
        __builtin_amdgcn_sched_barrier(0);  // loads above, compute below
        proc4v(P0, T0, sb, cw);
        proc4v(P1, T1, sb, cw);
        proc4v(P2, T2, sb, cw);
        proc4v(P3, T3, sb, cw);
    }
    // tail: any remaining float4s (n4 not divisible by 4*stride)
    for (int j = start + ngrp * 4 * stride; j < n4; j += stride) {
        float4 p = p4[j], t = t4[j];
        proc4v(p, t, sb, cw);
    }

    // -------- epilogue: wave reduce -> LDS -> one global atomic/bin/block ----
    __shared__ float        redS[BINS];
    __shared__ unsigned int redC[BINS];
    if (tid < BINS) { redS[tid] = 0.0f; redC[tid] = 0u; }
    __syncthreads();

    const int lane = tid & 63;
#pragma unroll
    for (int b = 0; b < BINS; ++b) {
        float s = sb[b];
#pragma unroll
        for (int off = 32; off > 0; off >>= 1) s += __shfl_down(s, off);
        if (lane == 0) {
            atomicAdd(&redS[b], s);
            atomicAdd(&redC[b], cw[b]);   // cw is wave-uniform (ballot-derived)
        }
    }
    __syncthreads();
    if (tid < BINS) {
        atomicAdd(&gsum[tid], redS[tid]);
        atomicAdd(&gcnt[tid], redC[tid]);
    }
}

__global__ void ghm_finalize(const float* __restrict__ gsum,
                             const unsigned int* __restrict__ gcnt,
                             float* __restrict__ out)
{
    if (threadIdx.x == 0 && blockIdx.x == 0) {
        int n = 0;
#pragma unroll
        for (int b = 0; b < BINS; ++b) n += (gcnt[b] > 0u) ? 1 : 0;
        float nn = (float)(n > 0 ? n : 1);
        float acc = 0.0f;
#pragma unroll
        for (int b = 0; b < BINS; ++b) {
            if (gcnt[b] > 0u)
                acc += gsum[b] / ((float)gcnt[b] * nn);  // counts < 2^24: exact
        }
        out[0] = -0.6931471805599453f * acc;   // fold -ln(2) from log2 domain
    }
}

extern "C" void kernel_launch(void* const* d_in, const int* in_sizes, int n_in,
                              void* d_out, int out_size, void* d_ws, size_t ws_size,
                              hipStream_t stream)
{
    const float* p = (const float*)d_in[0];   // inputs (probabilities)
    const float* t = (const float*)d_in[1];   // targets (0/1 floats)
    const int n  = in_sizes[0];               // 262144*128
    const int n4 = n >> 2;                    // divisible by 4

    float*        gsum = (float*)d_ws;
    unsigned int* gcnt = (unsigned int*)((char*)d_ws + BINS * sizeof(float));

    // d_ws is re-poisoned to 0xAA before every timed launch — zero it (capturable)
    hipMemsetAsync(d_ws, 0, BINS * (sizeof(float) + sizeof(unsigned int)), stream);

    const int threads = 256;
    const int blocks  = 2048;   // 16 float4/thread -> 4 bulk groups
    ghm_partial<<<blocks, threads, 0, stream>>>(
        (const float4*)p, (const float4*)t, gsum, gcnt, n4);

    ghm_finalize<<<1, 64, 0, stream>>>(gsum, gcnt, (float*)d_out);
}